// Round 2
// baseline (1728.586 us; speedup 1.0000x reference)
//
#include <hip/hip_runtime.h>
#include <stdint.h>

#define DIM 2048
#define HID 5632
#define SEQ 8192
#define NW3 (3*HID)            // 16896
#define CONV 4
#define CHUNK 64

typedef __attribute__((ext_vector_type(8))) __bf16 bf16x8;
typedef __attribute__((ext_vector_type(4))) float f32x4;

__device__ __forceinline__ uint16_t f2bf(float f) {
  union { float f; uint32_t u; } v; v.f = f;
  return (uint16_t)((v.u + 0x7FFFu + ((v.u >> 16) & 1u)) >> 16);
}
__device__ __forceinline__ float bf2f(uint16_t h) {
  union { uint32_t u; float f; } v; v.u = ((uint32_t)h) << 16;
  return v.f;
}

// ---------------- fp32 -> bf16 conversion (vectorized x4) ----------------
__global__ void cvt4_kernel(const float* __restrict__ src, uint16_t* __restrict__ dst, int n4) {
  int i = blockIdx.x * blockDim.x + threadIdx.x;
  if (i >= n4) return;
  float4 v = ((const float4*)src)[i];
  ushort4 o;
  o.x = f2bf(v.x); o.y = f2bf(v.y); o.z = f2bf(v.z); o.w = f2bf(v.w);
  ((ushort4*)dst)[i] = o;
}

__device__ __forceinline__ void load_lds16(const void* g, void* l) {
  __builtin_amdgcn_global_load_lds(
      (__attribute__((address_space(1))) void*)g,
      (__attribute__((address_space(3))) void*)l, 16, 0, 0);
}

// ---------------- 256x256 pipelined bf16 GEMM: C = A(M,K;LDA) * B(N,K;LDB)^T ----
// 512 threads = 8 waves (2M x 4N), BK=64, LDS 128 KiB double-buffered.
// LDS per (buf,khalf): [256][32] bf16, XOR swizzle phys_kslice = kslice^((row>>1)&3)
// (0 bank conflicts measured), applied as inverse-swizzled global source +
// swizzled ds_read (global_load_lds dest stays linear).
//
// SOFTWARE-PIPELINED phases (one fragment-set ahead; m196's "fine interleave"):
// each phase = { issue ds_reads for NEXT quadrant | issue 1 stage unit |
//   counted lgkmcnt (waits only PREVIOUS phase's reads) | sched_barrier |
//   setprio(1) 16 MFMA on resident frags setprio(0) | [vmcnt(6) 2x/K-tile] |
//   s_barrier | sched_barrier }.
// LDS pipe executes next-phase reads while matrix pipe drains current MFMAs.
// vmcnt(6) = 3 stage-units in flight (m201's N); never drained to 0 in loop.
// OUT_MODE: 0 = fp32 store, 1 = bf16 store, 2 = fp32 atomicAdd (split-K via blockIdx.y)
template<int LDA, int LDB, int LDC, int KLEN, int OUT_MODE>
__global__ __launch_bounds__(512, 2)
void gemm256(const uint16_t* __restrict__ A, const uint16_t* __restrict__ B,
             void* __restrict__ C, int nbx)
{
  __shared__ alignas(16) uint16_t As[2][2][256][32];
  __shared__ alignas(16) uint16_t Bs[2][2][256][32];
  constexpr int NT = KLEN / 64;

  const int tid  = threadIdx.x;
  const int wave = tid >> 6;
  const int lane = tid & 63;

  // bijective XCD-aware swizzle (m204)
  const int nwg = (int)gridDim.x;
  const int bid = (int)blockIdx.x;
  const int qq  = nwg >> 3, rr = nwg & 7;
  const int xcd = bid & 7, loc = bid >> 3;
  const int swz = (xcd < rr ? xcd*(qq+1) : rr*(qq+1) + (xcd-rr)*qq) + loc;
  const int row0 = (swz % nbx) * 256;
  const int col0 = (swz / nbx) * 256;

  const uint16_t* Ab = A + (size_t)blockIdx.y * KLEN;   // split-K slice
  const uint16_t* Bb = B + (size_t)blockIdx.y * KLEN;

  const int wr = wave >> 2;          // 0..1 -> rows wr*128..
  const int wc = wave & 3;           // 0..3 -> cols wc*64..
  const int rm = lane & 15;
  const int kq8 = ((lane >> 4) ^ ((rm >> 1) & 3)) * 8;  // swizzled k-slice (elems)
  const int ri = wr*128 + rm;
  const int ci = wc*64 + rm;

  // staging: granule g = j*512+tid holds logical row g>>2,
  // k-slice (g&3)^((row>>1)&3)  (inverse swizzle at the global source)
  size_t offA0, offA1, offB0, offB1;
  {
    const int g0 = tid,       r0_ = g0 >> 2, k0_ = (g0 & 3) ^ ((r0_ >> 1) & 3);
    const int g1 = 512 + tid, r1_ = g1 >> 2, k1_ = (g1 & 3) ^ ((r1_ >> 1) & 3);
    offA0 = (size_t)(row0 + r0_)*LDA + k0_*8;
    offA1 = (size_t)(row0 + r1_)*LDA + k1_*8;
    offB0 = (size_t)(col0 + r0_)*LDB + k0_*8;
    offB1 = (size_t)(col0 + r1_)*LDB + k1_*8;
  }

#define STAGE_A(kt,h,buf) do {                                              \
    const size_t ko_ = (size_t)(kt)*64 + (size_t)(h)*32;                    \
    load_lds16(Ab + offA0 + ko_, &As[(buf)][(h)][wave*16][0]);              \
    load_lds16(Ab + offA1 + ko_, &As[(buf)][(h)][128 + wave*16][0]);        \
  } while (0)
#define STAGE_B(kt,h,buf) do {                                              \
    const size_t ko_ = (size_t)(kt)*64 + (size_t)(h)*32;                    \
    load_lds16(Bb + offB0 + ko_, &Bs[(buf)][(h)][wave*16][0]);              \
    load_lds16(Bb + offB1 + ko_, &Bs[(buf)][(h)][128 + wave*16][0]);        \
  } while (0)
#define PIN() __builtin_amdgcn_sched_barrier(0)

  f32x4 acc[8][4];
  #pragma unroll
  for (int i = 0; i < 8; ++i)
    #pragma unroll
    for (int j = 0; j < 4; ++j) acc[i][j] = (f32x4){0.f,0.f,0.f,0.f};

  bf16x8 a0[4], a1[4], b0[4], b1[4];

  // prologue: tile0 kh0+kh1 -> buf0, tile1 kh0 -> buf1 (12 loads/thread)
  STAGE_A(0,0,0); STAGE_B(0,0,0);
  STAGE_A(0,1,0); STAGE_B(0,1,0);
  {
    const int t1 = (NT > 1) ? 1 : 0;
    STAGE_A(t1,0,1); STAGE_B(t1,0,1);
  }
  asm volatile("s_waitcnt vmcnt(8)" ::: "memory");
  __builtin_amdgcn_s_barrier();
  PIN();
  // preload Q0 fragments (tile0, kh0, A0-3 + B)
  #pragma unroll
  for (int i = 0; i < 4; ++i) a0[i] = *(const bf16x8*)&As[0][0][ri + i*16][kq8];
  #pragma unroll
  for (int j = 0; j < 4; ++j) b0[j] = *(const bf16x8*)&Bs[0][0][ci + j*16][kq8];

  #pragma unroll 1
  for (int t = 0; t < NT; ++t) {
    const int c   = t & 1;
    const int tn1 = (t+1 < NT) ? t+1 : NT-1;   // clamped (dummy) at tail
    const int tn2 = (t+2 < NT) ? t+2 : NT-1;

    // ---- P0: MFMA Q0 (kh0, A0-3) | preload A4-7 kh0 ----
    #pragma unroll
    for (int i = 0; i < 4; ++i) a1[i] = *(const bf16x8*)&As[c][0][ri + (i+4)*16][kq8];
    STAGE_A(tn1, 1, c^1);
    asm volatile("s_waitcnt lgkmcnt(4)" ::: "memory");
    PIN();
    __builtin_amdgcn_s_setprio(1);
    #pragma unroll
    for (int i = 0; i < 4; ++i)
      #pragma unroll
      for (int j = 0; j < 4; ++j)
        acc[i][j] = __builtin_amdgcn_mfma_f32_16x16x32_bf16(a0[i], b0[j], acc[i][j], 0, 0, 0);
    __builtin_amdgcn_s_setprio(0);
    asm volatile("s_waitcnt vmcnt(6)" ::: "memory");
    __builtin_amdgcn_s_barrier();
    PIN();

    // ---- P1: MFMA Q1 (kh0, A4-7) | preload A0-3 kh1 + B kh1 ----
    #pragma unroll
    for (int i = 0; i < 4; ++i) a0[i] = *(const bf16x8*)&As[c][1][ri + i*16][kq8];
    #pragma unroll
    for (int j = 0; j < 4; ++j) b1[j] = *(const bf16x8*)&Bs[c][1][ci + j*16][kq8];
    STAGE_B(tn1, 1, c^1);
    asm volatile("s_waitcnt lgkmcnt(8)" ::: "memory");
    PIN();
    __builtin_amdgcn_s_setprio(1);
    #pragma unroll
    for (int i = 0; i < 4; ++i)
      #pragma unroll
      for (int j = 0; j < 4; ++j)
        acc[i+4][j] = __builtin_amdgcn_mfma_f32_16x16x32_bf16(a1[i], b0[j], acc[i+4][j], 0, 0, 0);
    __builtin_amdgcn_s_setprio(0);
    __builtin_amdgcn_s_barrier();
    PIN();

    // ---- P2: MFMA Q2 (kh1, A0-3) | preload A4-7 kh1 ----
    #pragma unroll
    for (int i = 0; i < 4; ++i) a1[i] = *(const bf16x8*)&As[c][1][ri + (i+4)*16][kq8];
    STAGE_A(tn2, 0, c);
    asm volatile("s_waitcnt lgkmcnt(4)" ::: "memory");
    PIN();
    __builtin_amdgcn_s_setprio(1);
    #pragma unroll
    for (int i = 0; i < 4; ++i)
      #pragma unroll
      for (int j = 0; j < 4; ++j)
        acc[i][j] = __builtin_amdgcn_mfma_f32_16x16x32_bf16(a0[i], b1[j], acc[i][j], 0, 0, 0);
    __builtin_amdgcn_s_setprio(0);
    asm volatile("s_waitcnt vmcnt(6)" ::: "memory");
    __builtin_amdgcn_s_barrier();
    PIN();

    // ---- P3: MFMA Q3 (kh1, A4-7) | preload next-tile A0-3 kh0 + B kh0 ----
    #pragma unroll
    for (int i = 0; i < 4; ++i) a0[i] = *(const bf16x8*)&As[c^1][0][ri + i*16][kq8];
    #pragma unroll
    for (int j = 0; j < 4; ++j) b0[j] = *(const bf16x8*)&Bs[c^1][0][ci + j*16][kq8];
    STAGE_B(tn2, 0, c);
    asm volatile("s_waitcnt lgkmcnt(8)" ::: "memory");
    PIN();
    __builtin_amdgcn_s_setprio(1);
    #pragma unroll
    for (int i = 0; i < 4; ++i)
      #pragma unroll
      for (int j = 0; j < 4; ++j)
        acc[i+4][j] = __builtin_amdgcn_mfma_f32_16x16x32_bf16(a1[i], b1[j], acc[i+4][j], 0, 0, 0);
    __builtin_amdgcn_s_setprio(0);
    __builtin_amdgcn_s_barrier();
    PIN();
  }
#undef STAGE_A
#undef STAGE_B
#undef PIN

  // epilogue: C/D layout col=lane&15, row=(lane>>4)*4+reg
  const int cr = (lane >> 4) * 4;
  const int cc = lane & 15;
  #pragma unroll
  for (int i = 0; i < 8; ++i)
    #pragma unroll
    for (int j = 0; j < 4; ++j) {
      const int r_ = row0 + wr*128 + i*16 + cr;
      const int c_ = col0 + wc*64  + j*16 + cc;
      #pragma unroll
      for (int r = 0; r < 4; ++r) {
        const float v = acc[i][j][r];
        const size_t idx = (size_t)(r_ + r)*LDC + c_;
        if (OUT_MODE == 1)      ((uint16_t*)C)[idx] = f2bf(v);
        else if (OUT_MODE == 2) atomicAdd((float*)C + idx, v);
        else                    ((float*)C)[idx] = v;
      }
    }
}

// ---------------- segment helpers ----------------
// G layout per local row r (stride NW3): [0,HID)=w0, [HID,2HID)=z_pre, [2HID,3HID)=tilde_h

__device__ __forceinline__ void seg_info(const int* cuv, int ns, int t, int& ss, bool& st) {
  ss = 0; st = false;
  for (int i=0;i<ns;i++) { int cv = cuv[i]; if (cv<=t && cv>ss) ss=cv; if (cv==t) st=true; }
}

// ---------------- scan pass A: per-chunk conv+sigmoid+local scan ----------------
__global__ void scan_chunk(const uint16_t* __restrict__ G, int qstart,
                           const uint16_t* __restrict__ zprev,
                           const float* __restrict__ convw,
                           const int* __restrict__ cu, int ncu,
                           float* __restrict__ Ach, float* __restrict__ Bch)
{
  int h = blockIdx.x * blockDim.x + threadIdx.x;
  int c = blockIdx.y;
  if (h >= HID) return;
  const uint16_t* Z  = G + HID;
  const uint16_t* TH = G + 2*HID;
  float w0c = convw[h*4+0], w1c = convw[h*4+1], w2c = convw[h*4+2], w3c = convw[h*4+3];
  int cuv[8];
  int ns = ncu - 1; if (ns > 8) ns = 8;
  for (int i=0;i<ns;i++) cuv[i] = cu[i];
  int r0 = c * CHUNK;
  int t0 = qstart + r0;
  float z1, z2, z3;
  if (c == 0) {
    z1 = (t0-1 >= 0) ? bf2f(zprev[2*HID + h]) : 0.f;
    z2 = (t0-2 >= 0) ? bf2f(zprev[1*HID + h]) : 0.f;
    z3 = (t0-3 >= 0) ? bf2f(zprev[0*HID + h]) : 0.f;
  } else {
    z1 = bf2f(Z[(size_t)(r0-1)*NW3 + h]);
    z2 = bf2f(Z[(size_t)(r0-2)*NW3 + h]);
    z3 = bf2f(Z[(size_t)(r0-3)*NW3 + h]);
  }
  float Aacc = 1.f, Bacc = 0.f;
  for (int r = r0; r < r0 + CHUNK; ++r) {
    int t = qstart + r;
    float z0 = bf2f(Z[(size_t)r*NW3 + h]);
    float th = bf2f(TH[(size_t)r*NW3 + h]);
    int ss; bool st;
    seg_info(cuv, ns, t, ss, st);
    float s = z0*w3c;
    if (t-1 >= ss) s += z1*w2c;
    if (t-2 >= ss) s += z2*w1c;
    if (t-3 >= ss) s += z3*w0c;
    float zc = 1.f/(1.f + __expf(-s));
    float a = st ? 0.f : (1.f - zc);
    float b = zc * th;
    Aacc *= a;
    Bacc = a*Bacc + b;
    z3 = z2; z2 = z1; z1 = z0;
  }
  Ach[(size_t)c*HID + h] = Aacc;
  Bch[(size_t)c*HID + h] = Bacc;
}

// ---------------- scan pass B: combine chunk pairs; Hin written in place over Ach ----------------
__global__ void scan_combine(float* __restrict__ Ach, const float* __restrict__ Bch,
                             float* __restrict__ Sc, int first, int nchunk)
{
  int h = blockIdx.x * blockDim.x + threadIdx.x;
  if (h >= HID) return;
  float s = first ? 0.f : Sc[h];
  for (int c = 0; c < nchunk; ++c) {
    size_t idx = (size_t)c*HID + h;
    float a = Ach[idx], b = Bch[idx];
    Ach[idx] = s;                  // state entering chunk c (Hin)
    s = a*s + b;
  }
  Sc[h] = s;
}

// ---------------- scan pass C: fixup + h*silu(w0), hh written in place over TH ----------------
__global__ void scan_final(uint16_t* __restrict__ G, int qstart,
                           const uint16_t* __restrict__ zprev,
                           const float* __restrict__ convw,
                           const int* __restrict__ cu, int ncu,
                           const float* __restrict__ Hin)
{
  int h = blockIdx.x * blockDim.x + threadIdx.x;
  int c = blockIdx.y;
  if (h >= HID) return;
  const uint16_t* W0 = G;
  const uint16_t* Z  = G + HID;
  uint16_t*       TH = G + 2*HID;     // read th, then overwrite with hh
  float w0c = convw[h*4+0], w1c = convw[h*4+1], w2c = convw[h*4+2], w3c = convw[h*4+3];
  int cuv[8];
  int ns = ncu - 1; if (ns > 8) ns = 8;
  for (int i=0;i<ns;i++) cuv[i] = cu[i];
  int r0 = c * CHUNK;
  int t0 = qstart + r0;
  float z1, z2, z3;
  if (c == 0) {
    z1 = (t0-1 >= 0) ? bf2f(zprev[2*HID + h]) : 0.f;
    z2 = (t0-2 >= 0) ? bf2f(zprev[1*HID + h]) : 0.f;
    z3 = (t0-3 >= 0) ? bf2f(zprev[0*HID + h]) : 0.f;
  } else {
    z1 = bf2f(Z[(size_t)(r0-1)*NW3 + h]);
    z2 = bf2f(Z[(size_t)(r0-2)*NW3 + h]);
    z3 = bf2f(Z[(size_t)(r0-3)*NW3 + h]);
  }
  float state = Hin[(size_t)c*HID + h];
  for (int r = r0; r < r0 + CHUNK; ++r) {
    int t = qstart + r;
    float z0 = bf2f(Z[(size_t)r*NW3 + h]);
    float th = bf2f(TH[(size_t)r*NW3 + h]);
    int ss; bool st;
    seg_info(cuv, ns, t, ss, st);
    float s = z0*w3c;
    if (t-1 >= ss) s += z1*w2c;
    if (t-2 >= ss) s += z2*w1c;
    if (t-3 >= ss) s += z3*w0c;
    float zc = 1.f/(1.f + __expf(-s));
    float a = st ? 0.f : (1.f - zc);
    float b = zc * th;
    state = a*state + b;
    float w0v = bf2f(W0[(size_t)r*NW3 + h]);
    float silu = w0v / (1.f + __expf(-w0v));
    TH[(size_t)r*NW3 + h] = f2bf(state * silu);
    z3 = z2; z2 = z1; z1 = z0;
  }
}

// ---------------- save last 3 z-rows of this segment for next segment's conv taps ----------------
__global__ void save_ztail(const uint16_t* __restrict__ G, uint16_t* __restrict__ zprev, int qrows) {
  int i = blockIdx.x * blockDim.x + threadIdx.x;
  if (i >= 3*HID) return;
  int j = i / HID;        // 0,1,2 -> rows qrows-3+j
  int h = i - j*HID;
  zprev[i] = G[(size_t)(qrows-3+j)*NW3 + HID + h];
}

// ---------------- launcher ----------------
extern "C" void kernel_launch(void* const* d_in, const int* in_sizes, int n_in,
                              void* d_out, int out_size, void* d_ws, size_t ws_size,
                              hipStream_t stream) {
  const float* x     = (const float*)d_in[0];
  const int*   cu    = (const int*)d_in[1];
  const float* w_w   = (const float*)d_in[2];
  const float* wz_w  = (const float*)d_in[3];
  const float* wh_w  = (const float*)d_in[4];
  const float* wo_w  = (const float*)d_in[5];
  const float* convw = (const float*)d_in[6];
  const int ncu = in_sizes[1];
  float* out = (float*)d_out;

  // ---- tier selection: largest segment that fits ws ----
  const size_t base = 92331008ull;
  int qrows = 2048;
  if (ws_size >= base + 8192ull*38592ull) qrows = 8192;
  else if (ws_size >= base + 4096ull*38592ull) qrows = 4096;
  const int nq = SEQ / qrows;
  const int nchunk = qrows / CHUNK;

  // ---- workspace layout ----
  char* p = (char*)d_ws;
  uint16_t* w3b  = (uint16_t*)p; p += (size_t)NW3*DIM*2;       // 69.2 MB
  uint16_t* wob  = (uint16_t*)p; p += (size_t)DIM*HID*2;       // 23.1 MB
  float*    Sc   = (float*)p;    p += (size_t)HID*4;
  uint16_t* zprev= (uint16_t*)p; p += (size_t)3*HID*2;
  uint16_t* xseg = (uint16_t*)p; p += (size_t)qrows*DIM*2;
  uint16_t* G    = (uint16_t*)p; p += (size_t)qrows*NW3*2;
  float*    Ach  = (float*)p;    p += (size_t)nchunk*HID*4;    // doubles as Hin
  float*    Bch  = (float*)p;    p += (size_t)nchunk*HID*4;

  // ---- weight conversions (once) ----
  {
    int n4 = HID*DIM/4;
    cvt4_kernel<<<(n4+255)/256, 256, 0, stream>>>(w_w,  w3b, n4);
    cvt4_kernel<<<(n4+255)/256, 256, 0, stream>>>(wz_w, w3b + (size_t)HID*DIM, n4);
    cvt4_kernel<<<(n4+255)/256, 256, 0, stream>>>(wh_w, w3b + (size_t)2*HID*DIM, n4);
    n4 = DIM*HID/4;
    cvt4_kernel<<<(n4+255)/256, 256, 0, stream>>>(wo_w, wob, n4);
  }

  if (qrows < 8192)  // split-K atomics epilogue needs zeroed out
    hipMemsetAsync(out, 0, (size_t)out_size * sizeof(float), stream);

  for (int s = 0; s < nq; ++s) {
    const int qstart = s * qrows;

    // x segment -> bf16
    int n4 = qrows*DIM/4;
    cvt4_kernel<<<(n4+255)/256, 256, 0, stream>>>(x + (size_t)qstart*DIM, xseg, n4);

    // GEMM1: G = xseg @ [w_w;wz_w;wh_w]^T  (M=qrows, N=16896, K=2048)
    {
      const int nbx = qrows / 256;
      gemm256<DIM, DIM, NW3, DIM, 1><<<dim3(nbx * (NW3/256), 1), 512, 0, stream>>>(
          xseg, w3b, G, nbx);
    }

    // chunked scan with fused causal conv + gating
    scan_chunk  <<<dim3(HID/256, nchunk), 256, 0, stream>>>(G, qstart, zprev, convw, cu, ncu, Ach, Bch);
    scan_combine<<<HID/256, 256, 0, stream>>>(Ach, Bch, Sc, s == 0 ? 1 : 0, nchunk);
    scan_final  <<<dim3(HID/256, nchunk), 256, 0, stream>>>(G, qstart, zprev, convw, cu, ncu, Ach);

    if (s + 1 < nq)
      save_ztail<<<(3*HID+255)/256, 256, 0, stream>>>(G, zprev, qrows);

    // GEMM2: out[qstart:] = hh @ wo^T  (hh aliased over TH, lda=NW3; N=2048, K=5632)
    // split-K sized so total workgroups >= 256 (1 block/CU at 256^2 tiles)
    if (qrows == 8192) {
      gemm256<NW3, HID, DIM, HID, 0><<<dim3(32*(DIM/256), 1), 512, 0, stream>>>(
          G + 2*HID, wob, out + (size_t)qstart*DIM, 32);
    } else if (qrows == 4096) {
      gemm256<NW3, HID, DIM, HID/2, 2><<<dim3(16*(DIM/256), 2), 512, 0, stream>>>(
          G + 2*HID, wob, out + (size_t)qstart*DIM, 16);
    } else {
      gemm256<NW3, HID, DIM, HID/4, 2><<<dim3(8*(DIM/256), 4), 512, 0, stream>>>(
          G + 2*HID, wob, out + (size_t)qstart*DIM, 8);
    }
  }
}

// Round 3
// 1557.202 us; speedup vs baseline: 1.1101x; 1.1101x over previous
//
#include <hip/hip_runtime.h>
#include <stdint.h>

#define DIM 2048
#define HID 5632
#define SEQ 8192
#define NW3 (3*HID)            // 16896
#define CONV 4
#define CHUNK 64

typedef __attribute__((ext_vector_type(8))) __bf16 bf16x8;
typedef __attribute__((ext_vector_type(4))) float f32x4;
typedef __attribute__((ext_vector_type(4))) uint16_t u16x4;

__device__ __forceinline__ uint16_t f2bf(float f) {
  union { float f; uint32_t u; } v; v.f = f;
  return (uint16_t)((v.u + 0x7FFFu + ((v.u >> 16) & 1u)) >> 16);
}
__device__ __forceinline__ float bf2f(uint16_t h) {
  union { uint32_t u; float f; } v; v.u = ((uint32_t)h) << 16;
  return v.f;
}

// ---------------- fp32 -> bf16 conversion (vectorized x4) ----------------
__global__ void cvt4_kernel(const float* __restrict__ src, uint16_t* __restrict__ dst, int n4) {
  int i = blockIdx.x * blockDim.x + threadIdx.x;
  if (i >= n4) return;
  float4 v = ((const float4*)src)[i];
  ushort4 o;
  o.x = f2bf(v.x); o.y = f2bf(v.y); o.z = f2bf(v.z); o.w = f2bf(v.w);
  ((ushort4*)dst)[i] = o;
}

__device__ __forceinline__ void load_lds16(const void* g, void* l) {
  __builtin_amdgcn_global_load_lds(
      (__attribute__((address_space(1))) void*)g,
      (__attribute__((address_space(3))) void*)l, 16, 0, 0);
}

// ---------------- 256x256 4-phase bf16 GEMM: C = A(M,K;LDA) * B(N,K;LDB)^T ----
// (r1 structure: reads-in-phase + lgkmcnt(0); r2's reg-preload reverted — it
// regressed 376->408. Added sched_barrier(0) pins after stage-issue and after
// each phase-end barrier: C++ ds_reads are otherwise free to migrate across the
// raw s_barrier (latent race + scheduling hazard).)
// LDS per (buf,khalf): [256][32] bf16, XOR swizzle phys_kslice = kslice^((row>>1)&3)
// (0 bank conflicts measured), inverse-swizzled global source + swizzled ds_read.
// vmcnt(8) twice per K-tile (counted, never 0 in loop).
// OUT_MODE: 0 = fp32 store, 1 = bf16 store, 2 = fp32 atomicAdd (split-K via blockIdx.y)
template<int LDA, int LDB, int LDC, int KLEN, int OUT_MODE>
__global__ __launch_bounds__(512, 2)
void gemm256(const uint16_t* __restrict__ A, const uint16_t* __restrict__ B,
             void* __restrict__ C, int nbx)
{
  __shared__ alignas(16) uint16_t As[2][2][256][32];
  __shared__ alignas(16) uint16_t Bs[2][2][256][32];
  constexpr int NT = KLEN / 64;

  const int tid  = threadIdx.x;
  const int wave = tid >> 6;
  const int lane = tid & 63;

  // bijective XCD-aware swizzle (m204)
  const int nwg = (int)gridDim.x;
  const int bid = (int)blockIdx.x;
  const int qq  = nwg >> 3, rr = nwg & 7;
  const int xcd = bid & 7, loc = bid >> 3;
  const int swz = (xcd < rr ? xcd*(qq+1) : rr*(qq+1) + (xcd-rr)*qq) + loc;
  const int row0 = (swz % nbx) * 256;
  const int col0 = (swz / nbx) * 256;

  const uint16_t* Ab = A + (size_t)blockIdx.y * KLEN;   // split-K slice
  const uint16_t* Bb = B + (size_t)blockIdx.y * KLEN;

  const int wr = wave >> 2;          // 0..1 -> rows wr*128..
  const int wc = wave & 3;           // 0..3 -> cols wc*64..
  const int rm = lane & 15;
  const int kq8 = ((lane >> 4) ^ ((rm >> 1) & 3)) * 8;  // swizzled k-slice (elems)
  const int ri = wr*128 + rm;
  const int ci = wc*64 + rm;

  // staging: granule g = j*512+tid holds logical row g>>2,
  // k-slice (g&3)^((row>>1)&3)  (inverse swizzle at the global source)
  size_t offA0, offA1, offB0, offB1;
  {
    const int g0 = tid,       r0_ = g0 >> 2, k0_ = (g0 & 3) ^ ((r0_ >> 1) & 3);
    const int g1 = 512 + tid, r1_ = g1 >> 2, k1_ = (g1 & 3) ^ ((r1_ >> 1) & 3);
    offA0 = (size_t)(row0 + r0_)*LDA + k0_*8;
    offA1 = (size_t)(row0 + r1_)*LDA + k1_*8;
    offB0 = (size_t)(col0 + r0_)*LDB + k0_*8;
    offB1 = (size_t)(col0 + r1_)*LDB + k1_*8;
  }

#define STAGE_A(kt,h,buf) do {                                              \
    const size_t ko_ = (size_t)(kt)*64 + (size_t)(h)*32;                    \
    load_lds16(Ab + offA0 + ko_, &As[(buf)][(h)][wave*16][0]);              \
    load_lds16(Ab + offA1 + ko_, &As[(buf)][(h)][128 + wave*16][0]);        \
  } while (0)
#define STAGE_B(kt,h,buf) do {                                              \
    const size_t ko_ = (size_t)(kt)*64 + (size_t)(h)*32;                    \
    load_lds16(Bb + offB0 + ko_, &Bs[(buf)][(h)][wave*16][0]);              \
    load_lds16(Bb + offB1 + ko_, &Bs[(buf)][(h)][128 + wave*16][0]);        \
  } while (0)
#define PIN() __builtin_amdgcn_sched_barrier(0)

  f32x4 acc[8][4];
  #pragma unroll
  for (int i = 0; i < 8; ++i)
    #pragma unroll
    for (int j = 0; j < 4; ++j) acc[i][j] = (f32x4){0.f,0.f,0.f,0.f};

  // prologue: tile0 kh0+kh1 -> buf0, tile1 kh0 -> buf1 (12 loads/thread)
  STAGE_A(0,0,0); STAGE_B(0,0,0);
  STAGE_A(0,1,0); STAGE_B(0,1,0);
  {
    const int t1 = (NT > 1) ? 1 : 0;
    STAGE_A(t1,0,1); STAGE_B(t1,0,1);
  }
  asm volatile("s_waitcnt vmcnt(8)" ::: "memory");
  __builtin_amdgcn_s_barrier();
  PIN();

  #pragma unroll 1
  for (int t = 0; t < NT; ++t) {
    const int c   = t & 1;
    const int tn1 = (t+1 < NT) ? t+1 : NT-1;   // clamped (dummy) at tail
    const int tn2 = (t+2 < NT) ? t+2 : NT-1;
    bf16x8 af[4], bfr[4];

    // ---- phase 1: kh0, M-frags 0..3 ----
    #pragma unroll
    for (int i = 0; i < 4; ++i) af[i]  = *(const bf16x8*)&As[c][0][ri + i*16][kq8];
    #pragma unroll
    for (int j = 0; j < 4; ++j) bfr[j] = *(const bf16x8*)&Bs[c][0][ci + j*16][kq8];
    STAGE_A(tn1, 1, c^1);
    PIN();
    __builtin_amdgcn_s_barrier();
    asm volatile("s_waitcnt lgkmcnt(0)" ::: "memory");
    PIN();
    __builtin_amdgcn_s_setprio(1);
    #pragma unroll
    for (int i = 0; i < 4; ++i)
      #pragma unroll
      for (int j = 0; j < 4; ++j)
        acc[i][j] = __builtin_amdgcn_mfma_f32_16x16x32_bf16(af[i], bfr[j], acc[i][j], 0, 0, 0);
    __builtin_amdgcn_s_setprio(0);
    __builtin_amdgcn_s_barrier();
    PIN();

    // ---- phase 2: kh0, M-frags 4..7 ----
    #pragma unroll
    for (int i = 0; i < 4; ++i) af[i] = *(const bf16x8*)&As[c][0][ri + (i+4)*16][kq8];
    STAGE_B(tn1, 1, c^1);
    PIN();
    __builtin_amdgcn_s_barrier();
    asm volatile("s_waitcnt lgkmcnt(0)" ::: "memory");
    PIN();
    __builtin_amdgcn_s_setprio(1);
    #pragma unroll
    for (int i = 0; i < 4; ++i)
      #pragma unroll
      for (int j = 0; j < 4; ++j)
        acc[i+4][j] = __builtin_amdgcn_mfma_f32_16x16x32_bf16(af[i], bfr[j], acc[i+4][j], 0, 0, 0);
    __builtin_amdgcn_s_setprio(0);
    asm volatile("s_waitcnt vmcnt(8)" ::: "memory");   // kh1 of tile t landed
    __builtin_amdgcn_s_barrier();
    PIN();

    // ---- phase 3: kh1, M-frags 0..3 ----
    #pragma unroll
    for (int i = 0; i < 4; ++i) af[i]  = *(const bf16x8*)&As[c][1][ri + i*16][kq8];
    #pragma unroll
    for (int j = 0; j < 4; ++j) bfr[j] = *(const bf16x8*)&Bs[c][1][ci + j*16][kq8];
    STAGE_A(tn2, 0, c);
    PIN();
    __builtin_amdgcn_s_barrier();
    asm volatile("s_waitcnt lgkmcnt(0)" ::: "memory");
    PIN();
    __builtin_amdgcn_s_setprio(1);
    #pragma unroll
    for (int i = 0; i < 4; ++i)
      #pragma unroll
      for (int j = 0; j < 4; ++j)
        acc[i][j] = __builtin_amdgcn_mfma_f32_16x16x32_bf16(af[i], bfr[j], acc[i][j], 0, 0, 0);
    __builtin_amdgcn_s_setprio(0);
    __builtin_amdgcn_s_barrier();
    PIN();

    // ---- phase 4: kh1, M-frags 4..7 ----
    #pragma unroll
    for (int i = 0; i < 4; ++i) af[i] = *(const bf16x8*)&As[c][1][ri + (i+4)*16][kq8];
    STAGE_B(tn2, 0, c);
    PIN();
    __builtin_amdgcn_s_barrier();
    asm volatile("s_waitcnt lgkmcnt(0)" ::: "memory");
    PIN();
    __builtin_amdgcn_s_setprio(1);
    #pragma unroll
    for (int i = 0; i < 4; ++i)
      #pragma unroll
      for (int j = 0; j < 4; ++j)
        acc[i+4][j] = __builtin_amdgcn_mfma_f32_16x16x32_bf16(af[i], bfr[j], acc[i+4][j], 0, 0, 0);
    __builtin_amdgcn_s_setprio(0);
    asm volatile("s_waitcnt vmcnt(8)" ::: "memory");   // kh0 of tile t+1 landed
    __builtin_amdgcn_s_barrier();
    PIN();
  }
#undef STAGE_A
#undef STAGE_B
#undef PIN

  // epilogue: C/D layout col=lane&15, row=(lane>>4)*4+reg
  const int cr = (lane >> 4) * 4;
  const int cc = lane & 15;
  #pragma unroll
  for (int i = 0; i < 8; ++i)
    #pragma unroll
    for (int j = 0; j < 4; ++j) {
      const int r_ = row0 + wr*128 + i*16 + cr;
      const int c_ = col0 + wc*64  + j*16 + cc;
      #pragma unroll
      for (int r = 0; r < 4; ++r) {
        const float v = acc[i][j][r];
        const size_t idx = (size_t)(r_ + r)*LDC + c_;
        if (OUT_MODE == 1)      ((uint16_t*)C)[idx] = f2bf(v);
        else if (OUT_MODE == 2) atomicAdd((float*)C + idx, v);
        else                    ((float*)C)[idx] = v;
      }
    }
}

// ---------------- segment helpers ----------------
// G layout per local row r (stride NW3): [0,HID)=w0, [HID,2HID)=z_pre, [2HID,3HID)=tilde_h

__device__ __forceinline__ void seg_info(const int* cuv, int ns, int t, int& ss, bool& st) {
  ss = 0; st = false;
  for (int i=0;i<ns;i++) { int cv = cuv[i]; if (cv<=t && cv>ss) ss=cv; if (cv==t) st=true; }
}

// ---------------- scan pass A: per-chunk conv+sigmoid+local scan (VEC=4) ----------------
// 1408 h-threads (4 h-cols each), ushort4 8B/lane loads, 1-row-ahead prefetch.
__global__ void scan_chunk(const uint16_t* __restrict__ G, int qstart,
                           const uint16_t* __restrict__ zprev,
                           const float* __restrict__ convw,
                           const int* __restrict__ cu, int ncu,
                           float* __restrict__ Ach, float* __restrict__ Bch)
{
  const int h0 = (blockIdx.x * blockDim.x + threadIdx.x) * 4;   // 11*128*4 = 5632
  const int c  = blockIdx.y;
  const uint16_t* Z  = G + HID;
  const uint16_t* TH = G + 2*HID;
  float4 wv[4];
  #pragma unroll
  for (int j=0;j<4;j++) wv[j] = ((const float4*)convw)[h0+j];
  int cuv[8];
  int ns = ncu - 1; if (ns > 8) ns = 8;
  for (int i=0;i<ns;i++) cuv[i] = cu[i];
  const int r0 = c * CHUNK;
  const int t0 = qstart + r0;
  float z1[4], z2[4], z3[4];
  if (c == 0) {
    u16x4 a1 = *(const u16x4*)&zprev[2*HID + h0];
    u16x4 a2 = *(const u16x4*)&zprev[1*HID + h0];
    u16x4 a3 = *(const u16x4*)&zprev[0*HID + h0];
    #pragma unroll
    for (int j=0;j<4;j++) {
      z1[j] = (t0-1 >= 0) ? bf2f(a1[j]) : 0.f;
      z2[j] = (t0-2 >= 0) ? bf2f(a2[j]) : 0.f;
      z3[j] = (t0-3 >= 0) ? bf2f(a3[j]) : 0.f;
    }
  } else {
    u16x4 a1 = *(const u16x4*)&Z[(size_t)(r0-1)*NW3 + h0];
    u16x4 a2 = *(const u16x4*)&Z[(size_t)(r0-2)*NW3 + h0];
    u16x4 a3 = *(const u16x4*)&Z[(size_t)(r0-3)*NW3 + h0];
    #pragma unroll
    for (int j=0;j<4;j++) { z1[j]=bf2f(a1[j]); z2[j]=bf2f(a2[j]); z3[j]=bf2f(a3[j]); }
  }
  float Aacc[4] = {1.f,1.f,1.f,1.f};
  float Bacc[4] = {0.f,0.f,0.f,0.f};
  u16x4 zv = *(const u16x4*)&Z[(size_t)r0*NW3 + h0];
  u16x4 tv = *(const u16x4*)&TH[(size_t)r0*NW3 + h0];
  for (int r = r0; r < r0 + CHUNK; ++r) {
    const int rn = (r+1 < r0+CHUNK) ? r+1 : r;   // clamped prefetch (in-bounds)
    u16x4 zn = *(const u16x4*)&Z[(size_t)rn*NW3 + h0];
    u16x4 tn = *(const u16x4*)&TH[(size_t)rn*NW3 + h0];
    const int t = qstart + r;
    int ss; bool st;
    seg_info(cuv, ns, t, ss, st);
    const bool k1 = (t-1 >= ss), k2 = (t-2 >= ss), k3 = (t-3 >= ss);
    #pragma unroll
    for (int j=0;j<4;j++) {
      const float zc0 = bf2f(zv[j]);
      float s = zc0*wv[j].w;
      if (k1) s += z1[j]*wv[j].z;
      if (k2) s += z2[j]*wv[j].y;
      if (k3) s += z3[j]*wv[j].x;
      const float zc = 1.f/(1.f + __expf(-s));
      const float a = st ? 0.f : (1.f - zc);
      const float b = zc * bf2f(tv[j]);
      Aacc[j] *= a;
      Bacc[j] = a*Bacc[j] + b;
      z3[j] = z2[j]; z2[j] = z1[j]; z1[j] = zc0;
    }
    zv = zn; tv = tn;
  }
  *(float4*)&Ach[(size_t)c*HID + h0] = make_float4(Aacc[0],Aacc[1],Aacc[2],Aacc[3]);
  *(float4*)&Bch[(size_t)c*HID + h0] = make_float4(Bacc[0],Bacc[1],Bacc[2],Bacc[3]);
}

// ---------------- scan pass B: combine chunks (float4); Hin in place over Ach ----------------
__global__ void scan_combine(float* __restrict__ Ach, const float* __restrict__ Bch,
                             float* __restrict__ Sc, int first, int nchunk)
{
  const int h0 = (blockIdx.x * blockDim.x + threadIdx.x) * 4;
  float4 s;
  if (first) s = make_float4(0.f,0.f,0.f,0.f);
  else       s = *(const float4*)&Sc[h0];
  for (int c = 0; c < nchunk; ++c) {
    const size_t idx = (size_t)c*HID + h0;
    float4 a = *(const float4*)&Ach[idx];
    float4 b = *(const float4*)&Bch[idx];
    *(float4*)&Ach[idx] = s;                  // state entering chunk c (Hin)
    s.x = a.x*s.x + b.x;
    s.y = a.y*s.y + b.y;
    s.z = a.z*s.z + b.z;
    s.w = a.w*s.w + b.w;
  }
  *(float4*)&Sc[h0] = s;
}

// ---------------- scan pass C: fixup + h*silu(w0) (VEC=4), hh in place over TH ----------------
__global__ void scan_final(uint16_t* __restrict__ G, int qstart,
                           const uint16_t* __restrict__ zprev,
                           const float* __restrict__ convw,
                           const int* __restrict__ cu, int ncu,
                           const float* __restrict__ Hin)
{
  const int h0 = (blockIdx.x * blockDim.x + threadIdx.x) * 4;
  const int c  = blockIdx.y;
  const uint16_t* W0 = G;
  const uint16_t* Z  = G + HID;
  uint16_t*       TH = G + 2*HID;     // read th, then overwrite with hh
  float4 wv[4];
  #pragma unroll
  for (int j=0;j<4;j++) wv[j] = ((const float4*)convw)[h0+j];
  int cuv[8];
  int ns = ncu - 1; if (ns > 8) ns = 8;
  for (int i=0;i<ns;i++) cuv[i] = cu[i];
  const int r0 = c * CHUNK;
  const int t0 = qstart + r0;
  float z1[4], z2[4], z3[4];
  if (c == 0) {
    u16x4 a1 = *(const u16x4*)&zprev[2*HID + h0];
    u16x4 a2 = *(const u16x4*)&zprev[1*HID + h0];
    u16x4 a3 = *(const u16x4*)&zprev[0*HID + h0];
    #pragma unroll
    for (int j=0;j<4;j++) {
      z1[j] = (t0-1 >= 0) ? bf2f(a1[j]) : 0.f;
      z2[j] = (t0-2 >= 0) ? bf2f(a2[j]) : 0.f;
      z3[j] = (t0-3 >= 0) ? bf2f(a3[j]) : 0.f;
    }
  } else {
    u16x4 a1 = *(const u16x4*)&Z[(size_t)(r0-1)*NW3 + h0];
    u16x4 a2 = *(const u16x4*)&Z[(size_t)(r0-2)*NW3 + h0];
    u16x4 a3 = *(const u16x4*)&Z[(size_t)(r0-3)*NW3 + h0];
    #pragma unroll
    for (int j=0;j<4;j++) { z1[j]=bf2f(a1[j]); z2[j]=bf2f(a2[j]); z3[j]=bf2f(a3[j]); }
  }
  float state[4];
  {
    float4 hv = *(const float4*)&Hin[(size_t)c*HID + h0];
    state[0]=hv.x; state[1]=hv.y; state[2]=hv.z; state[3]=hv.w;
  }
  u16x4 zv = *(const u16x4*)&Z[(size_t)r0*NW3 + h0];
  u16x4 tv = *(const u16x4*)&TH[(size_t)r0*NW3 + h0];
  u16x4 wvv = *(const u16x4*)&W0[(size_t)r0*NW3 + h0];
  for (int r = r0; r < r0 + CHUNK; ++r) {
    const int rn = (r+1 < r0+CHUNK) ? r+1 : r;
    u16x4 zn = *(const u16x4*)&Z[(size_t)rn*NW3 + h0];
    u16x4 tn = *(const u16x4*)&TH[(size_t)rn*NW3 + h0];
    u16x4 wn = *(const u16x4*)&W0[(size_t)rn*NW3 + h0];
    const int t = qstart + r;
    int ss; bool st;
    seg_info(cuv, ns, t, ss, st);
    const bool k1 = (t-1 >= ss), k2 = (t-2 >= ss), k3 = (t-3 >= ss);
    u16x4 outv;
    #pragma unroll
    for (int j=0;j<4;j++) {
      const float zc0 = bf2f(zv[j]);
      float s = zc0*wv[j].w;
      if (k1) s += z1[j]*wv[j].z;
      if (k2) s += z2[j]*wv[j].y;
      if (k3) s += z3[j]*wv[j].x;
      const float zc = 1.f/(1.f + __expf(-s));
      const float a = st ? 0.f : (1.f - zc);
      const float b = zc * bf2f(tv[j]);
      state[j] = a*state[j] + b;
      const float w0v = bf2f(wvv[j]);
      const float silu = w0v / (1.f + __expf(-w0v));
      outv[j] = f2bf(state[j] * silu);
      z3[j] = z2[j]; z2[j] = z1[j]; z1[j] = zc0;
    }
    *(u16x4*)&TH[(size_t)r*NW3 + h0] = outv;
    zv = zn; tv = tn; wvv = wn;
  }
}

// ---------------- save last 3 z-rows for next segment's conv taps (ushort4) ----------------
__global__ void save_ztail(const uint16_t* __restrict__ G, uint16_t* __restrict__ zprev, int qrows) {
  int i4 = (blockIdx.x * blockDim.x + threadIdx.x) * 4;
  if (i4 >= 3*HID) return;
  int j = i4 / HID;        // HID%4==0 so a ushort4 never straddles rows
  int h = i4 - j*HID;
  *(u16x4*)&zprev[i4] = *(const u16x4*)&G[(size_t)(qrows-3+j)*NW3 + HID + h];
}

// ---------------- launcher ----------------
extern "C" void kernel_launch(void* const* d_in, const int* in_sizes, int n_in,
                              void* d_out, int out_size, void* d_ws, size_t ws_size,
                              hipStream_t stream) {
  const float* x     = (const float*)d_in[0];
  const int*   cu    = (const int*)d_in[1];
  const float* w_w   = (const float*)d_in[2];
  const float* wz_w  = (const float*)d_in[3];
  const float* wh_w  = (const float*)d_in[4];
  const float* wo_w  = (const float*)d_in[5];
  const float* convw = (const float*)d_in[6];
  const int ncu = in_sizes[1];
  float* out = (float*)d_out;

  // ---- tier selection: largest segment that fits ws ----
  const size_t base = 92331008ull;
  int qrows = 2048;
  if (ws_size >= base + 8192ull*38592ull) qrows = 8192;
  else if (ws_size >= base + 4096ull*38592ull) qrows = 4096;
  const int nq = SEQ / qrows;
  const int nchunk = qrows / CHUNK;

  // ---- workspace layout ----
  char* p = (char*)d_ws;
  uint16_t* w3b  = (uint16_t*)p; p += (size_t)NW3*DIM*2;       // 69.2 MB
  uint16_t* wob  = (uint16_t*)p; p += (size_t)DIM*HID*2;       // 23.1 MB
  float*    Sc   = (float*)p;    p += (size_t)HID*4;
  uint16_t* zprev= (uint16_t*)p; p += (size_t)3*HID*2;
  uint16_t* xseg = (uint16_t*)p; p += (size_t)qrows*DIM*2;
  uint16_t* G    = (uint16_t*)p; p += (size_t)qrows*NW3*2;
  float*    Ach  = (float*)p;    p += (size_t)nchunk*HID*4;    // doubles as Hin
  float*    Bch  = (float*)p;    p += (size_t)nchunk*HID*4;

  // ---- weight conversions (once) ----
  {
    int n4 = HID*DIM/4;
    cvt4_kernel<<<(n4+255)/256, 256, 0, stream>>>(w_w,  w3b, n4);
    cvt4_kernel<<<(n4+255)/256, 256, 0, stream>>>(wz_w, w3b + (size_t)HID*DIM, n4);
    cvt4_kernel<<<(n4+255)/256, 256, 0, stream>>>(wh_w, w3b + (size_t)2*HID*DIM, n4);
    n4 = DIM*HID/4;
    cvt4_kernel<<<(n4+255)/256, 256, 0, stream>>>(wo_w, wob, n4);
  }

  if (qrows < 8192)  // split-K atomics epilogue needs zeroed out
    hipMemsetAsync(out, 0, (size_t)out_size * sizeof(float), stream);

  for (int s = 0; s < nq; ++s) {
    const int qstart = s * qrows;

    // x segment -> bf16
    int n4 = qrows*DIM/4;
    cvt4_kernel<<<(n4+255)/256, 256, 0, stream>>>(x + (size_t)qstart*DIM, xseg, n4);

    // GEMM1: G = xseg @ [w_w;wz_w;wh_w]^T  (M=qrows, N=16896, K=2048)
    {
      const int nbx = qrows / 256;
      gemm256<DIM, DIM, NW3, DIM, 1><<<dim3(nbx * (NW3/256), 1), 512, 0, stream>>>(
          xseg, w3b, G, nbx);
    }

    // chunked scan with fused causal conv + gating (h-vectorized x4)
    scan_chunk  <<<dim3(11, nchunk), 128, 0, stream>>>(G, qstart, zprev, convw, cu, ncu, Ach, Bch);
    scan_combine<<<11, 128, 0, stream>>>(Ach, Bch, Sc, s == 0 ? 1 : 0, nchunk);
    scan_final  <<<dim3(11, nchunk), 128, 0, stream>>>(G, qstart, zprev, convw, cu, ncu, Ach);

    if (s + 1 < nq)
      save_ztail<<<(3*HID/4+127)/128, 128, 0, stream>>>(G, zprev, qrows);

    // GEMM2: out[qstart:] = hh @ wo^T  (hh aliased over TH, lda=NW3; N=2048, K=5632)
    if (qrows == 8192) {
      gemm256<NW3, HID, DIM, HID, 0><<<dim3(32*(DIM/256), 1), 512, 0, stream>>>(
          G + 2*HID, wob, out + (size_t)qstart*DIM, 32);
    } else if (qrows == 4096) {
      gemm256<NW3, HID, DIM, HID/2, 2><<<dim3(16*(DIM/256), 2), 512, 0, stream>>>(
          G + 2*HID, wob, out + (size_t)qstart*DIM, 16);
    } else {
      gemm256<NW3, HID, DIM, HID/4, 2><<<dim3(8*(DIM/256), 4), 512, 0, stream>>>(
          G + 2*HID, wob, out + (size_t)qstart*DIM, 8);
    }
  }
}

// Round 4
// 1385.402 us; speedup vs baseline: 1.2477x; 1.1240x over previous
//
#include <hip/hip_runtime.h>
#include <stdint.h>

#define DIM 2048
#define HID 5632
#define SEQ 8192
#define NW3 (3*HID)            // 16896
#define CONV 4
#define CHUNK 64
#define PLDC 8448              // fp32 stride of partial buffer aliased over G rows

typedef __attribute__((ext_vector_type(8))) __bf16 bf16x8;
typedef __attribute__((ext_vector_type(4))) float f32x4;
typedef __attribute__((ext_vector_type(4))) uint16_t u16x4;

__device__ __forceinline__ uint16_t f2bf(float f) {
  union { float f; uint32_t u; } v; v.f = f;
  return (uint16_t)((v.u + 0x7FFFu + ((v.u >> 16) & 1u)) >> 16);
}
__device__ __forceinline__ float bf2f(uint16_t h) {
  union { uint32_t u; float f; } v; v.u = ((uint32_t)h) << 16;
  return v.f;
}

// ---------------- fp32 -> bf16 conversion (vectorized x4) ----------------
__global__ void cvt4_kernel(const float* __restrict__ src, uint16_t* __restrict__ dst, int n4) {
  int i = blockIdx.x * blockDim.x + threadIdx.x;
  if (i >= n4) return;
  float4 v = ((const float4*)src)[i];
  ushort4 o;
  o.x = f2bf(v.x); o.y = f2bf(v.y); o.z = f2bf(v.z); o.w = f2bf(v.w);
  ((ushort4*)dst)[i] = o;
}

__device__ __forceinline__ void load_lds16(const void* g, void* l) {
  __builtin_amdgcn_global_load_lds(
      (__attribute__((address_space(1))) void*)g,
      (__attribute__((address_space(3))) void*)l, 16, 0, 0);
}

// ---------------- 128x256 / BK=32 / 3-buf bf16 GEMM: C = A(M,K;LDA)*B(N,K;LDB)^T
// Occupancy-first redesign: LDS 72 KiB (3 bufs), <=128 VGPR -> 2 blocks/CU
// (16 waves/CU). Co-resident block hides barrier/lgkm/vmcnt drains (m114
// mechanism) that capped the 1-block/CU 256^2 variants at ~32% MfmaUtil.
// 8 waves (2M x 4N), per-wave 64x64 out (acc=64 VGPR).
// LDS per buf: A[128][32] + B[256][32] bf16, XOR swizzle
//   phys_kslice = kslice ^ ((row>>1)&3)   (0 conflicts, HW-verified r1-r3)
// inverse-swizzled global source + swizzled ds_read; gload_lds dest linear.
// Per K-tile: { 8 ds_read | STAGE(t+2 -> (t+2)%3): 3 loads | lgkmcnt(0)+PIN |
//   setprio(1) 16 MFMA setprio(0) | vmcnt(3) | barrier } — vmcnt counted,
// never 0 in loop (STAGE(t+1) landed, STAGE(t+2) in flight).
// OUT_MODE: 0 = fp32 store to C; 1 = bf16 store to C;
//           2 = split-K dual store: z==0 -> fp32 C2 (LDC2), z==1 -> fp32 C.
template<int LDA, int LDB, int LDC, int LDC2, int KLEN, int OUT_MODE>
__global__ __launch_bounds__(512, 4)
void gemm128(const uint16_t* __restrict__ A, const uint16_t* __restrict__ B,
             void* __restrict__ C, float* __restrict__ C2, int nbx)
{
  __shared__ alignas(16) uint16_t As[3][128][32];
  __shared__ alignas(16) uint16_t Bs[3][256][32];
  constexpr int NT = KLEN / 32;

  const int tid  = threadIdx.x;
  const int wave = tid >> 6;
  const int lane = tid & 63;

  // bijective XCD-aware swizzle (m204); grid.x divisible by 8 in all uses
  const int nwg = (int)gridDim.x;
  const int bid = (int)blockIdx.x;
  const int qq  = nwg >> 3, rr = nwg & 7;
  const int xcd = bid & 7, loc = bid >> 3;
  const int swz = (xcd < rr ? xcd*(qq+1) : rr*(qq+1) + (xcd-rr)*qq) + loc;
  const int row0 = (swz % nbx) * 128;
  const int col0 = (swz / nbx) * 256;

  const uint16_t* Ab = A + (size_t)blockIdx.z * KLEN;   // split-K slice
  const uint16_t* Bb = B + (size_t)blockIdx.z * KLEN;

  const int wr = wave >> 2;          // 0..1 -> rows wr*64..
  const int wc = wave & 3;           // 0..3 -> cols wc*64..
  const int rm = lane & 15;
  const int kq8 = ((lane >> 4) ^ ((rm >> 1) & 3)) * 8;  // swizzled k-slice (elems)
  const int ri = wr*64 + rm;
  const int ci = wc*64 + rm;

  // staging: granule g holds logical row g>>2, k-slice (g&3)^((row>>1)&3)
  // (inverse swizzle at the global source; LDS dest stays linear)
  size_t offA, offB0, offB1;
  {
    const int ra = tid >> 2,        ka = (tid & 3) ^ ((ra >> 1) & 3);
    const int rb0 = tid >> 2,       kb0 = (tid & 3) ^ ((rb0 >> 1) & 3);
    const int g1 = 512 + tid;
    const int rb1 = g1 >> 2,        kb1 = (g1 & 3) ^ ((rb1 >> 1) & 3);
    offA  = (size_t)(row0 + ra)*LDA + ka*8;
    offB0 = (size_t)(col0 + rb0)*LDB + kb0*8;
    offB1 = (size_t)(col0 + rb1)*LDB + kb1*8;
  }

#define STAGE(kt,buf) do {                                                  \
    const size_t ko_ = (size_t)(kt)*32;                                     \
    load_lds16(Ab + offA  + ko_, &As[(buf)][wave*16][0]);                   \
    load_lds16(Bb + offB0 + ko_, &Bs[(buf)][wave*16][0]);                   \
    load_lds16(Bb + offB1 + ko_, &Bs[(buf)][128 + wave*16][0]);             \
  } while (0)
#define PIN() __builtin_amdgcn_sched_barrier(0)

  f32x4 acc[4][4];
  #pragma unroll
  for (int i = 0; i < 4; ++i)
    #pragma unroll
    for (int j = 0; j < 4; ++j) acc[i][j] = (f32x4){0.f,0.f,0.f,0.f};

  // prologue: tile0 -> buf0, tile1 -> buf1
  STAGE(0, 0);
  {
    const int t1 = (NT > 1) ? 1 : 0;
    STAGE(t1, 1);
  }
  asm volatile("s_waitcnt vmcnt(3)" ::: "memory");   // tile0 landed
  __builtin_amdgcn_s_barrier();
  PIN();

  int c = 0;
  #pragma unroll 1
  for (int t = 0; t < NT; ++t) {
    const int tn2 = (t+2 < NT) ? t+2 : NT-1;   // clamped (dummy) at tail
    int cs = c + 2; if (cs >= 3) cs -= 3;      // buf for tile t+2

    bf16x8 af[4], bfr[4];
    #pragma unroll
    for (int i = 0; i < 4; ++i) af[i]  = *(const bf16x8*)&As[c][ri + i*16][kq8];
    #pragma unroll
    for (int j = 0; j < 4; ++j) bfr[j] = *(const bf16x8*)&Bs[c][ci + j*16][kq8];
    STAGE(tn2, cs);
    PIN();
    asm volatile("s_waitcnt lgkmcnt(0)" ::: "memory");
    PIN();
    __builtin_amdgcn_s_setprio(1);
    #pragma unroll
    for (int i = 0; i < 4; ++i)
      #pragma unroll
      for (int j = 0; j < 4; ++j)
        acc[i][j] = __builtin_amdgcn_mfma_f32_16x16x32_bf16(af[i], bfr[j], acc[i][j], 0, 0, 0);
    __builtin_amdgcn_s_setprio(0);
    asm volatile("s_waitcnt vmcnt(3)" ::: "memory");  // STAGE(t+1) landed; t+2 in flight
    __builtin_amdgcn_s_barrier();
    PIN();

    c += 1; if (c >= 3) c = 0;
  }
#undef STAGE
#undef PIN

  // epilogue: C/D layout col=lane&15, row=(lane>>4)*4+reg
  const int cr = (lane >> 4) * 4;
  const int cc = lane & 15;
  #pragma unroll
  for (int i = 0; i < 4; ++i)
    #pragma unroll
    for (int j = 0; j < 4; ++j) {
      const int r_ = row0 + wr*64 + i*16 + cr;
      const int c_ = col0 + wc*64 + j*16 + cc;
      #pragma unroll
      for (int r = 0; r < 4; ++r) {
        const float v = acc[i][j][r];
        if (OUT_MODE == 1) {
          ((uint16_t*)C)[(size_t)(r_ + r)*LDC + c_] = f2bf(v);
        } else if (OUT_MODE == 2) {
          if (blockIdx.z == 0) C2[(size_t)(r_ + r)*LDC2 + c_] = v;
          else                 ((float*)C)[(size_t)(r_ + r)*LDC + c_] = v;
        } else {
          ((float*)C)[(size_t)(r_ + r)*LDC + c_] = v;
        }
      }
    }
}

// ---------------- merge split-K partial: out += P (P strided PLDC) ----------------
__global__ void addP_kernel(float* __restrict__ out, const float* __restrict__ P, int n4) {
  int i = blockIdx.x * blockDim.x + threadIdx.x;
  if (i >= n4) return;
  int r  = i >> 9;             // DIM/4 = 512 float4 per row
  int c4 = i & 511;
  float4 a = ((float4*)out)[i];
  float4 b = *(const float4*)&P[(size_t)r*PLDC + c4*4];
  a.x += b.x; a.y += b.y; a.z += b.z; a.w += b.w;
  ((float4*)out)[i] = a;
}

// ---------------- segment helpers ----------------
// G layout per local row r (stride NW3): [0,HID)=w0, [HID,2HID)=z_pre, [2HID,3HID)=tilde_h

__device__ __forceinline__ void seg_info(const int* cuv, int ns, int t, int& ss, bool& st) {
  ss = 0; st = false;
  for (int i=0;i<ns;i++) { int cv = cuv[i]; if (cv<=t && cv>ss) ss=cv; if (cv==t) st=true; }
}

// ---------------- scan pass A: per-chunk conv+sigmoid+local scan (VEC=4) ----------------
__global__ void scan_chunk(const uint16_t* __restrict__ G, int qstart,
                           const uint16_t* __restrict__ zprev,
                           const float* __restrict__ convw,
                           const int* __restrict__ cu, int ncu,
                           float* __restrict__ Ach, float* __restrict__ Bch)
{
  const int h0 = (blockIdx.x * blockDim.x + threadIdx.x) * 4;   // 11*128*4 = 5632
  const int c  = blockIdx.y;
  const uint16_t* Z  = G + HID;
  const uint16_t* TH = G + 2*HID;
  float4 wv[4];
  #pragma unroll
  for (int j=0;j<4;j++) wv[j] = ((const float4*)convw)[h0+j];
  int cuv[8];
  int ns = ncu - 1; if (ns > 8) ns = 8;
  for (int i=0;i<ns;i++) cuv[i] = cu[i];
  const int r0 = c * CHUNK;
  const int t0 = qstart + r0;
  float z1[4], z2[4], z3[4];
  if (c == 0) {
    u16x4 a1 = *(const u16x4*)&zprev[2*HID + h0];
    u16x4 a2 = *(const u16x4*)&zprev[1*HID + h0];
    u16x4 a3 = *(const u16x4*)&zprev[0*HID + h0];
    #pragma unroll
    for (int j=0;j<4;j++) {
      z1[j] = (t0-1 >= 0) ? bf2f(a1[j]) : 0.f;
      z2[j] = (t0-2 >= 0) ? bf2f(a2[j]) : 0.f;
      z3[j] = (t0-3 >= 0) ? bf2f(a3[j]) : 0.f;
    }
  } else {
    u16x4 a1 = *(const u16x4*)&Z[(size_t)(r0-1)*NW3 + h0];
    u16x4 a2 = *(const u16x4*)&Z[(size_t)(r0-2)*NW3 + h0];
    u16x4 a3 = *(const u16x4*)&Z[(size_t)(r0-3)*NW3 + h0];
    #pragma unroll
    for (int j=0;j<4;j++) { z1[j]=bf2f(a1[j]); z2[j]=bf2f(a2[j]); z3[j]=bf2f(a3[j]); }
  }
  float Aacc[4] = {1.f,1.f,1.f,1.f};
  float Bacc[4] = {0.f,0.f,0.f,0.f};
  u16x4 zv = *(const u16x4*)&Z[(size_t)r0*NW3 + h0];
  u16x4 tv = *(const u16x4*)&TH[(size_t)r0*NW3 + h0];
  for (int r = r0; r < r0 + CHUNK; ++r) {
    const int rn = (r+1 < r0+CHUNK) ? r+1 : r;   // clamped prefetch (in-bounds)
    u16x4 zn = *(const u16x4*)&Z[(size_t)rn*NW3 + h0];
    u16x4 tn = *(const u16x4*)&TH[(size_t)rn*NW3 + h0];
    const int t = qstart + r;
    int ss; bool st;
    seg_info(cuv, ns, t, ss, st);
    const bool k1 = (t-1 >= ss), k2 = (t-2 >= ss), k3 = (t-3 >= ss);
    #pragma unroll
    for (int j=0;j<4;j++) {
      const float zc0 = bf2f(zv[j]);
      float s = zc0*wv[j].w;
      if (k1) s += z1[j]*wv[j].z;
      if (k2) s += z2[j]*wv[j].y;
      if (k3) s += z3[j]*wv[j].x;
      const float zc = 1.f/(1.f + __expf(-s));
      const float a = st ? 0.f : (1.f - zc);
      const float b = zc * bf2f(tv[j]);
      Aacc[j] *= a;
      Bacc[j] = a*Bacc[j] + b;
      z3[j] = z2[j]; z2[j] = z1[j]; z1[j] = zc0;
    }
    zv = zn; tv = tn;
  }
  *(float4*)&Ach[(size_t)c*HID + h0] = make_float4(Aacc[0],Aacc[1],Aacc[2],Aacc[3]);
  *(float4*)&Bch[(size_t)c*HID + h0] = make_float4(Bacc[0],Bacc[1],Bacc[2],Bacc[3]);
}

// ---------------- scan pass B: combine chunks (float4); Hin in place over Ach ----------------
__global__ void scan_combine(float* __restrict__ Ach, const float* __restrict__ Bch,
                             float* __restrict__ Sc, int first, int nchunk)
{
  const int h0 = (blockIdx.x * blockDim.x + threadIdx.x) * 4;
  float4 s;
  if (first) s = make_float4(0.f,0.f,0.f,0.f);
  else       s = *(const float4*)&Sc[h0];
  for (int c = 0; c < nchunk; ++c) {
    const size_t idx = (size_t)c*HID + h0;
    float4 a = *(const float4*)&Ach[idx];
    float4 b = *(const float4*)&Bch[idx];
    *(float4*)&Ach[idx] = s;                  // state entering chunk c (Hin)
    s.x = a.x*s.x + b.x;
    s.y = a.y*s.y + b.y;
    s.z = a.z*s.z + b.z;
    s.w = a.w*s.w + b.w;
  }
  *(float4*)&Sc[h0] = s;
}

// ---------------- scan pass C: fixup + h*silu(w0) (VEC=4), hh in place over TH ----------------
__global__ void scan_final(uint16_t* __restrict__ G, int qstart,
                           const uint16_t* __restrict__ zprev,
                           const float* __restrict__ convw,
                           const int* __restrict__ cu, int ncu,
                           const float* __restrict__ Hin)
{
  const int h0 = (blockIdx.x * blockDim.x + threadIdx.x) * 4;
  const int c  = blockIdx.y;
  const uint16_t* W0 = G;
  const uint16_t* Z  = G + HID;
  uint16_t*       TH = G + 2*HID;     // read th, then overwrite with hh
  float4 wv[4];
  #pragma unroll
  for (int j=0;j<4;j++) wv[j] = ((const float4*)convw)[h0+j];
  int cuv[8];
  int ns = ncu - 1; if (ns > 8) ns = 8;
  for (int i=0;i<ns;i++) cuv[i] = cu[i];
  const int r0 = c * CHUNK;
  const int t0 = qstart + r0;
  float z1[4], z2[4], z3[4];
  if (c == 0) {
    u16x4 a1 = *(const u16x4*)&zprev[2*HID + h0];
    u16x4 a2 = *(const u16x4*)&zprev[1*HID + h0];
    u16x4 a3 = *(const u16x4*)&zprev[0*HID + h0];
    #pragma unroll
    for (int j=0;j<4;j++) {
      z1[j] = (t0-1 >= 0) ? bf2f(a1[j]) : 0.f;
      z2[j] = (t0-2 >= 0) ? bf2f(a2[j]) : 0.f;
      z3[j] = (t0-3 >= 0) ? bf2f(a3[j]) : 0.f;
    }
  } else {
    u16x4 a1 = *(const u16x4*)&Z[(size_t)(r0-1)*NW3 + h0];
    u16x4 a2 = *(const u16x4*)&Z[(size_t)(r0-2)*NW3 + h0];
    u16x4 a3 = *(const u16x4*)&Z[(size_t)(r0-3)*NW3 + h0];
    #pragma unroll
    for (int j=0;j<4;j++) { z1[j]=bf2f(a1[j]); z2[j]=bf2f(a2[j]); z3[j]=bf2f(a3[j]); }
  }
  float state[4];
  {
    float4 hv = *(const float4*)&Hin[(size_t)c*HID + h0];
    state[0]=hv.x; state[1]=hv.y; state[2]=hv.z; state[3]=hv.w;
  }
  u16x4 zv = *(const u16x4*)&Z[(size_t)r0*NW3 + h0];
  u16x4 tv = *(const u16x4*)&TH[(size_t)r0*NW3 + h0];
  u16x4 wvv = *(const u16x4*)&W0[(size_t)r0*NW3 + h0];
  for (int r = r0; r < r0 + CHUNK; ++r) {
    const int rn = (r+1 < r0+CHUNK) ? r+1 : r;
    u16x4 zn = *(const u16x4*)&Z[(size_t)rn*NW3 + h0];
    u16x4 tn = *(const u16x4*)&TH[(size_t)rn*NW3 + h0];
    u16x4 wn = *(const u16x4*)&W0[(size_t)rn*NW3 + h0];
    const int t = qstart + r;
    int ss; bool st;
    seg_info(cuv, ns, t, ss, st);
    const bool k1 = (t-1 >= ss), k2 = (t-2 >= ss), k3 = (t-3 >= ss);
    u16x4 outv;
    #pragma unroll
    for (int j=0;j<4;j++) {
      const float zc0 = bf2f(zv[j]);
      float s = zc0*wv[j].w;
      if (k1) s += z1[j]*wv[j].z;
      if (k2) s += z2[j]*wv[j].y;
      if (k3) s += z3[j]*wv[j].x;
      const float zc = 1.f/(1.f + __expf(-s));
      const float a = st ? 0.f : (1.f - zc);
      const float b = zc * bf2f(tv[j]);
      state[j] = a*state[j] + b;
      const float w0v = bf2f(wvv[j]);
      const float silu = w0v / (1.f + __expf(-w0v));
      outv[j] = f2bf(state[j] * silu);
      z3[j] = z2[j]; z2[j] = z1[j]; z1[j] = zc0;
    }
    *(u16x4*)&TH[(size_t)r*NW3 + h0] = outv;
    zv = zn; tv = tn; wvv = wn;
  }
}

// ---------------- save last 3 z-rows for next segment's conv taps (ushort4) ----------------
__global__ void save_ztail(const uint16_t* __restrict__ G, uint16_t* __restrict__ zprev, int qrows) {
  int i4 = (blockIdx.x * blockDim.x + threadIdx.x) * 4;
  if (i4 >= 3*HID) return;
  int j = i4 / HID;        // HID%4==0 so a ushort4 never straddles rows
  int h = i4 - j*HID;
  *(u16x4*)&zprev[i4] = *(const u16x4*)&G[(size_t)(qrows-3+j)*NW3 + HID + h];
}

// ---------------- launcher ----------------
extern "C" void kernel_launch(void* const* d_in, const int* in_sizes, int n_in,
                              void* d_out, int out_size, void* d_ws, size_t ws_size,
                              hipStream_t stream) {
  const float* x     = (const float*)d_in[0];
  const int*   cu    = (const int*)d_in[1];
  const float* w_w   = (const float*)d_in[2];
  const float* wz_w  = (const float*)d_in[3];
  const float* wh_w  = (const float*)d_in[4];
  const float* wo_w  = (const float*)d_in[5];
  const float* convw = (const float*)d_in[6];
  const int ncu = in_sizes[1];
  float* out = (float*)d_out;

  // ---- tier selection: largest segment that fits ws ----
  const size_t base = 92331008ull;
  int qrows = 2048;
  if (ws_size >= base + 8192ull*38592ull) qrows = 8192;
  else if (ws_size >= base + 4096ull*38592ull) qrows = 4096;
  const int nq = SEQ / qrows;
  const int nchunk = qrows / CHUNK;

  // ---- workspace layout ----
  char* p = (char*)d_ws;
  uint16_t* w3b  = (uint16_t*)p; p += (size_t)NW3*DIM*2;       // 69.2 MB
  uint16_t* wob  = (uint16_t*)p; p += (size_t)DIM*HID*2;       // 23.1 MB
  float*    Sc   = (float*)p;    p += (size_t)HID*4;
  uint16_t* zprev= (uint16_t*)p; p += (size_t)3*HID*2;
  uint16_t* xseg = (uint16_t*)p; p += (size_t)qrows*DIM*2;
  uint16_t* G    = (uint16_t*)p; p += (size_t)qrows*NW3*2;
  float*    Ach  = (float*)p;    p += (size_t)nchunk*HID*4;    // doubles as Hin
  float*    Bch  = (float*)p;    p += (size_t)nchunk*HID*4;

  // ---- weight conversions (once) ----
  {
    int n4 = HID*DIM/4;
    cvt4_kernel<<<(n4+255)/256, 256, 0, stream>>>(w_w,  w3b, n4);
    cvt4_kernel<<<(n4+255)/256, 256, 0, stream>>>(wz_w, w3b + (size_t)HID*DIM, n4);
    cvt4_kernel<<<(n4+255)/256, 256, 0, stream>>>(wh_w, w3b + (size_t)2*HID*DIM, n4);
    n4 = DIM*HID/4;
    cvt4_kernel<<<(n4+255)/256, 256, 0, stream>>>(wo_w, wob, n4);
  }

  for (int s = 0; s < nq; ++s) {
    const int qstart = s * qrows;

    // x segment -> bf16
    int n4 = qrows*DIM/4;
    cvt4_kernel<<<(n4+255)/256, 256, 0, stream>>>(x + (size_t)qstart*DIM, xseg, n4);

    // GEMM1: G = xseg @ [w_w;wz_w;wh_w]^T  (M=qrows, N=16896, K=2048)
    {
      const int nbx = qrows / 128;
      gemm128<DIM, DIM, NW3, 0, DIM, 1><<<dim3(nbx * (NW3/256), 1, 1), 512, 0, stream>>>(
          xseg, w3b, G, nullptr, nbx);
    }

    // chunked scan with fused causal conv + gating (h-vectorized x4)
    scan_chunk  <<<dim3(11, nchunk), 128, 0, stream>>>(G, qstart, zprev, convw, cu, ncu, Ach, Bch);
    scan_combine<<<11, 128, 0, stream>>>(Ach, Bch, Sc, s == 0 ? 1 : 0, nchunk);
    scan_final  <<<dim3(11, nchunk), 128, 0, stream>>>(G, qstart, zprev, convw, cu, ncu, Ach);

    if (s + 1 < nq)
      save_ztail<<<(3*HID/4+127)/128, 128, 0, stream>>>(G, zprev, qrows);

    // GEMM2: out[qstart:] = hh @ wo^T  (hh aliased over TH, lda=NW3; N=2048, K=5632)
    // split-K=2, no atomics: slice0 -> fp32 partial P aliased over G's dead W0
    // slot (stride PLDC floats), slice1 -> out; then out += P.
    const int nbx2 = qrows / 128;
    float* P = (float*)G;    // W0 region per row: bytes [0,11264) >= 8192 needed
    if (qrows == 8192) {
      gemm128<NW3, HID, DIM, 0, HID, 0><<<dim3(nbx2*(DIM/256), 1, 1), 512, 0, stream>>>(
          G + 2*HID, wob, out + (size_t)qstart*DIM, nullptr, nbx2);
    } else {
      gemm128<NW3, HID, DIM, PLDC, HID/2, 2><<<dim3(nbx2*(DIM/256), 1, 2), 512, 0, stream>>>(
          G + 2*HID, wob, out + (size_t)qstart*DIM, P, nbx2);
      int na = qrows * (DIM/4);
      addP_kernel<<<(na+255)/256, 256, 0, stream>>>(out + (size_t)qstart*DIM, P, na);
    }
  }
}